// Round 1
// baseline (171.336 us; speedup 1.0000x reference)
//
#include <hip/hip_runtime.h>

#define NN 4096
#define NFEAT 256
#define NHID 16
#define NHEADS 8
#define NCLASS 16
#define MAXN 256
#define LALPHA 0.2f

// ---------------------------------------------------------------------------
// Kernel A: compact dense adj (~1% nnz + self loops) into per-row neighbor
// lists. One block per row; 256 threads stream the 16 KB row as float4.
// ---------------------------------------------------------------------------
__global__ void build_nbr_kernel(const float* __restrict__ adj,
                                 int* __restrict__ nbr, int* __restrict__ cnt) {
  int row = blockIdx.x;
  const float4* arow = reinterpret_cast<const float4*>(adj + (size_t)row * NN);
  __shared__ int scnt;
  if (threadIdx.x == 0) scnt = 0;
  __syncthreads();
  int* rn = nbr + (size_t)row * MAXN;
#pragma unroll
  for (int it = 0; it < NN / 4 / 256; ++it) {
    int q = threadIdx.x + it * 256;
    float4 v = arow[q];
    int base = q * 4;
    if (v.x > 0.f) { int p = atomicAdd(&scnt, 1); if (p < MAXN) rn[p] = base + 0; }
    if (v.y > 0.f) { int p = atomicAdd(&scnt, 1); if (p < MAXN) rn[p] = base + 1; }
    if (v.z > 0.f) { int p = atomicAdd(&scnt, 1); if (p < MAXN) rn[p] = base + 2; }
    if (v.w > 0.f) { int p = atomicAdd(&scnt, 1); if (p < MAXN) rn[p] = base + 3; }
  }
  __syncthreads();
  if (threadIdx.x == 0) cnt[row] = scnt < MAXN ? scnt : MAXN;
}

// ---------------------------------------------------------------------------
// Kernel B: Wh1[n][h][d] = dot(x[n,:], W[h][:,d]); src1/dst1 logit projections.
// One block (128 threads = 8 heads x 16 dims) per node; x row staged in LDS.
// ---------------------------------------------------------------------------
__global__ void layer1_proj_kernel(const float* __restrict__ x,
                                   const float* __restrict__ W,
                                   const float* __restrict__ a_src,
                                   const float* __restrict__ a_dst,
                                   float* __restrict__ Wh1,
                                   float* __restrict__ src1,
                                   float* __restrict__ dst1) {
  int n = blockIdx.x;
  int t = threadIdx.x;  // 128
  __shared__ float xs[NFEAT];
  reinterpret_cast<float2*>(xs)[t] =
      reinterpret_cast<const float2*>(x + (size_t)n * NFEAT)[t];
  __syncthreads();
  int h = t >> 4, d = t & 15;
  const float* Wp = W + h * (NFEAT * NHID) + d;
  float acc = 0.f;
#pragma unroll 16
  for (int f = 0; f < NFEAT; ++f) acc += xs[f] * Wp[f * NHID];
  Wh1[(size_t)n * (NHEADS * NHID) + t] = acc;
  float vs = acc * a_src[h * NHID + d];
  float vd = acc * a_dst[h * NHID + d];
#pragma unroll
  for (int off = 8; off >= 1; off >>= 1) {
    vs += __shfl_xor(vs, off);  // 16-lane groups stay inside the wave
    vd += __shfl_xor(vd, off);
  }
  if (d == 0) {
    src1[n * NHEADS + h] = vs;
    dst1[n * NHEADS + h] = vd;
  }
}

// ---------------------------------------------------------------------------
// Kernel C: layer-1 masked softmax + aggregation + ELU, fused with the
// layer-2 projection (Wh2 = h_cat @ W_out, src2/dst2).
// One block (128 threads) per node. e-scores for all (nbr, head) in LDS.
// ---------------------------------------------------------------------------
__global__ void layer1_agg_kernel(const int* __restrict__ nbr, const int* __restrict__ cnt,
                                  const float* __restrict__ Wh1,
                                  const float* __restrict__ src1, const float* __restrict__ dst1,
                                  const float* __restrict__ Wout,
                                  const float* __restrict__ a2s, const float* __restrict__ a2d,
                                  float* __restrict__ Wh2, float* __restrict__ src2,
                                  float* __restrict__ dst2) {
  int n = blockIdx.x;
  int t = threadIdx.x;  // 128
  int h = t >> 4;
  int c = cnt[n];
  const int* nb = nbr + (size_t)n * MAXN;
  __shared__ float e[MAXN * NHEADS];  // 8 KB
  __shared__ float mh[NHEADS], rs[NHEADS];
  __shared__ float hs[NHEADS * NHID];
  // pass 1: raw leaky-relu scores for every (neighbor, head)
  for (int idx = t; idx < c * NHEADS; idx += 128) {
    int j = idx >> 3, hh = idx & 7;
    float ee = src1[n * NHEADS + hh] + dst1[nb[j] * NHEADS + hh];
    ee = ee > 0.f ? ee : LALPHA * ee;
    e[idx] = ee;
  }
  __syncthreads();
  // per-head max + sum
  if (t < NHEADS) {
    float m = -1e30f;
    for (int j = 0; j < c; ++j) m = fmaxf(m, e[j * NHEADS + t]);
    float s = 0.f;
    for (int j = 0; j < c; ++j) s += expf(e[j * NHEADS + t] - m);
    mh[t] = m;
    rs[t] = 1.f / s;
  }
  __syncthreads();
  // normalize weights in place
  for (int idx = t; idx < c * NHEADS; idx += 128) {
    int hh = idx & 7;
    e[idx] = expf(e[idx] - mh[hh]) * rs[hh];
  }
  __syncthreads();
  // aggregate neighbors
  float acc = 0.f;
  for (int j = 0; j < c; ++j)
    acc += e[j * NHEADS + h] * Wh1[(size_t)nb[j] * (NHEADS * NHID) + t];
  // ELU (concat=True layer)
  float hv = acc > 0.f ? acc : (expf(acc) - 1.f);
  hs[t] = hv;
  __syncthreads();
  // fused layer-2 projection: Wh2[n][cc] = sum_k hs[k] * Wout[k][cc]
  if (t < NCLASS) {
    float a = 0.f;
#pragma unroll 16
    for (int k = 0; k < NHEADS * NHID; ++k) a += hs[k] * Wout[k * NCLASS + t];
    Wh2[n * NCLASS + t] = a;
    float vs = a * a2s[t];
    float vd = a * a2d[t];
#pragma unroll
    for (int off = 8; off >= 1; off >>= 1) {
      vs += __shfl_xor(vs, off);
      vd += __shfl_xor(vd, off);
    }
    if (t == 0) {
      src2[n] = vs;
      dst2[n] = vd;
    }
  }
}

// ---------------------------------------------------------------------------
// Kernel D: layer-2 masked softmax + aggregation + final ELU.
// 16 threads per node (16 nodes per 256-thread block).
// ---------------------------------------------------------------------------
__global__ void layer2_agg_kernel(const int* __restrict__ nbr, const int* __restrict__ cnt,
                                  const float* __restrict__ Wh2,
                                  const float* __restrict__ src2, const float* __restrict__ dst2,
                                  float* __restrict__ out) {
  int g = threadIdx.x >> 4, d = threadIdx.x & 15;
  int n = blockIdx.x * 16 + g;
  int c = cnt[n];
  const int* nb = nbr + (size_t)n * MAXN;
  float si = src2[n];
  float m = -1e30f;
  for (int j = 0; j < c; ++j) {
    float ee = si + dst2[nb[j]];
    ee = ee > 0.f ? ee : LALPHA * ee;
    m = fmaxf(m, ee);
  }
  float s = 0.f, acc = 0.f;
  for (int j = 0; j < c; ++j) {
    int jj = nb[j];
    float ee = si + dst2[jj];
    ee = ee > 0.f ? ee : LALPHA * ee;
    float w = expf(ee - m);
    s += w;
    acc += w * Wh2[jj * NCLASS + d];
  }
  acc /= s;
  out[n * NCLASS + d] = acc > 0.f ? acc : (expf(acc) - 1.f);
}

extern "C" void kernel_launch(void* const* d_in, const int* in_sizes, int n_in,
                              void* d_out, int out_size, void* d_ws, size_t ws_size,
                              hipStream_t stream) {
  const float* x     = (const float*)d_in[0];
  const float* adj   = (const float*)d_in[1];
  const float* W     = (const float*)d_in[2];
  const float* a_src = (const float*)d_in[3];
  const float* a_dst = (const float*)d_in[4];
  const float* W_out = (const float*)d_in[5];
  const float* a_os  = (const float*)d_in[6];
  const float* a_od  = (const float*)d_in[7];
  float* out = (float*)d_out;

  char* ws = (char*)d_ws;
  size_t off = 0;
  auto alloc = [&](size_t bytes) -> void* {
    void* p = ws + off;
    off += (bytes + 255) & ~(size_t)255;
    return p;
  };
  int*   nbr  = (int*)alloc((size_t)NN * MAXN * sizeof(int));   // 4 MB
  int*   cnt  = (int*)alloc((size_t)NN * sizeof(int));
  float* Wh1  = (float*)alloc((size_t)NN * NHEADS * NHID * sizeof(float));  // 2 MB
  float* src1 = (float*)alloc((size_t)NN * NHEADS * sizeof(float));
  float* dst1 = (float*)alloc((size_t)NN * NHEADS * sizeof(float));
  float* Wh2  = (float*)alloc((size_t)NN * NCLASS * sizeof(float));
  float* src2 = (float*)alloc((size_t)NN * sizeof(float));
  float* dst2 = (float*)alloc((size_t)NN * sizeof(float));

  hipLaunchKernelGGL(build_nbr_kernel, dim3(NN), dim3(256), 0, stream, adj, nbr, cnt);
  hipLaunchKernelGGL(layer1_proj_kernel, dim3(NN), dim3(128), 0, stream,
                     x, W, a_src, a_dst, Wh1, src1, dst1);
  hipLaunchKernelGGL(layer1_agg_kernel, dim3(NN), dim3(128), 0, stream,
                     nbr, cnt, Wh1, src1, dst1, W_out, a_os, a_od, Wh2, src2, dst2);
  hipLaunchKernelGGL(layer2_agg_kernel, dim3(NN / 16), dim3(256), 0, stream,
                     nbr, cnt, Wh2, src2, dst2, out);
}

// Round 4
// 165.534 us; speedup vs baseline: 1.0350x; 1.0350x over previous
//
#include <hip/hip_runtime.h>

#define NN 4096
#define NFEAT 256
#define NHID 16
#define NHEADS 8
#define NCOL 128   // NHEADS*NHID
#define NCLASS 16
#define MAXN 256
#define LALPHA 0.2f
#define BNODES 16  // nodes per projection tile
#define XPAD 20    // xT row stride in floats (16 + 4 pad, keeps 16B alignment)
#define EPAD 260   // e row stride: 260%32=4 -> <=2-way bank conflict on writes

// ---------------------------------------------------------------------------
// Fused prep kernel.
//   blocks [0, NN):        compact adj row -> neighbor list (ballot, no
//                          per-element atomics)   [HBM-streaming]
//   blocks [NN, NN+256):   16-node tile of Wh1 = x@W + src1/dst1 logits,
//                          register-blocked 2x4 per thread  [VALU-bound]
// The two halves overlap on the device.
// ---------------------------------------------------------------------------
__global__ __launch_bounds__(256) void prep_kernel(
    const float* __restrict__ adj, const float* __restrict__ x,
    const float* __restrict__ W, const float* __restrict__ a_src,
    const float* __restrict__ a_dst,
    int* __restrict__ nbr, int* __restrict__ cnt,
    float* __restrict__ Wh1, float* __restrict__ src1, float* __restrict__ dst1) {
  __shared__ float xT[NFEAT * XPAD];  // 20 KB (B path)
  __shared__ int scnt;                // (A path)
  int t = threadIdx.x;

  if (blockIdx.x < NN) {
    // ---- A: compact one adjacency row via wave ballot ----
    int row = blockIdx.x;
    const float4* arow = reinterpret_cast<const float4*>(adj + (size_t)row * NN);
    if (t == 0) scnt = 0;
    __syncthreads();
    int* rn = nbr + (size_t)row * MAXN;
    int lane = t & 63;
    unsigned long long below = lane ? (~0ULL >> (64 - lane)) : 0ULL;
#pragma unroll
    for (int it = 0; it < NN / 4 / 256; ++it) {
      int q = t + it * 256;
      float4 v = arow[q];
      int base = q * 4;
      unsigned long long m0 = __ballot(v.x > 0.f);
      unsigned long long m1 = __ballot(v.y > 0.f);
      unsigned long long m2 = __ballot(v.z > 0.f);
      unsigned long long m3 = __ballot(v.w > 0.f);
      int c0 = __popcll(m0), c1 = __popcll(m1), c2 = __popcll(m2), c3 = __popcll(m3);
      int tot = c0 + c1 + c2 + c3;
      int wbase = 0;
      if (lane == 0 && tot) wbase = atomicAdd(&scnt, tot);
      wbase = __shfl(wbase, 0);
      if (v.x > 0.f) { int p = wbase + __popcll(m0 & below);           if (p < MAXN) rn[p] = base;     }
      if (v.y > 0.f) { int p = wbase + c0 + __popcll(m1 & below);      if (p < MAXN) rn[p] = base + 1; }
      if (v.z > 0.f) { int p = wbase + c0 + c1 + __popcll(m2 & below); if (p < MAXN) rn[p] = base + 2; }
      if (v.w > 0.f) { int p = wbase + c0 + c1 + c2 + __popcll(m3 & below); if (p < MAXN) rn[p] = base + 3; }
    }
    __syncthreads();
    if (t == 0) cnt[row] = scnt < MAXN ? scnt : MAXN;
  } else {
    // ---- B: projection tile ----
    int bn = (blockIdx.x - NN) * BNODES;
    // stage x[bn..bn+15][:] transposed: xT[f][node]
#pragma unroll
    for (int it = 0; it < BNODES; ++it) {
      xT[t * XPAD + it] = x[(size_t)(bn + it) * NFEAT + t];
    }
    __syncthreads();
    int cg = t & 31, ng = t >> 5;  // cols cg*4..+3, nodes ng*2..+1
    const float* Wp = W + (cg >> 2) * (NFEAT * NHID) + ((cg & 3) << 2);
    float acc[2][4] = {};
#pragma unroll 4
    for (int f = 0; f < NFEAT; ++f) {
      float4 wv = *reinterpret_cast<const float4*>(Wp + f * NHID);
      float2 xv = *reinterpret_cast<const float2*>(&xT[f * XPAD + ng * 2]);
      acc[0][0] += xv.x * wv.x; acc[0][1] += xv.x * wv.y;
      acc[0][2] += xv.x * wv.z; acc[0][3] += xv.x * wv.w;
      acc[1][0] += xv.y * wv.x; acc[1][1] += xv.y * wv.y;
      acc[1][2] += xv.y * wv.z; acc[1][3] += xv.y * wv.w;
    }
    int col0 = cg * 4;
    float4 as4 = *reinterpret_cast<const float4*>(a_src + col0);
    float4 ad4 = *reinterpret_cast<const float4*>(a_dst + col0);
#pragma unroll
    for (int i = 0; i < 2; ++i) {
      int n = bn + ng * 2 + i;
      *reinterpret_cast<float4*>(Wh1 + (size_t)n * NCOL + col0) =
          make_float4(acc[i][0], acc[i][1], acc[i][2], acc[i][3]);
      float vs = acc[i][0] * as4.x + acc[i][1] * as4.y + acc[i][2] * as4.z + acc[i][3] * as4.w;
      float vd = acc[i][0] * ad4.x + acc[i][1] * ad4.y + acc[i][2] * ad4.z + acc[i][3] * ad4.w;
      vs += __shfl_xor(vs, 1); vs += __shfl_xor(vs, 2);
      vd += __shfl_xor(vd, 1); vd += __shfl_xor(vd, 2);
      if ((cg & 3) == 0) {
        src1[n * NHEADS + (cg >> 2)] = vs;
        dst1[n * NHEADS + (cg >> 2)] = vd;
      }
    }
  }
}

// ---------------------------------------------------------------------------
// Layer-1 masked softmax + aggregation + ELU, fused with layer-2 projection.
// One block (128 threads = 8 heads x 16) per node. Softmax parallel across
// 16 lanes/head; 1/s folded into the epilogue (no normalize pass).
// ---------------------------------------------------------------------------
__global__ __launch_bounds__(128) void layer1_agg_kernel(
    const int* __restrict__ nbr, const int* __restrict__ cnt,
    const float* __restrict__ Wh1, const float* __restrict__ src1,
    const float* __restrict__ dst1, const float* __restrict__ Wout,
    const float* __restrict__ a2s, const float* __restrict__ a2d,
    float* __restrict__ Wh2, float* __restrict__ src2, float* __restrict__ dst2) {
  int n = blockIdx.x, t = threadIdx.x;
  int h = t >> 4, l = t & 15;
  int c = cnt[n];
  __shared__ int snb[MAXN];
  __shared__ float e[NHEADS * EPAD];
  __shared__ float hs[NCOL];
  __shared__ float part[NHEADS][NCLASS];
  for (int j = t; j < c; j += 128) snb[j] = nbr[(size_t)n * MAXN + j];
  __syncthreads();
  // scores e[h][j] = leaky(src1[n,h] + dst1[nbr,h])
  for (int idx = t; idx < c * NHEADS; idx += 128) {
    int j = idx >> 3, hh = idx & 7;
    float ee = src1[n * NHEADS + hh] + dst1[snb[j] * NHEADS + hh];
    e[hh * EPAD + j] = ee > 0.f ? ee : LALPHA * ee;
  }
  __syncthreads();
  // per-head max + exp-sum, 16 lanes per head
  float m = -1e30f;
  for (int j = l; j < c; j += 16) m = fmaxf(m, e[h * EPAD + j]);
  m = fmaxf(m, __shfl_xor(m, 8)); m = fmaxf(m, __shfl_xor(m, 4));
  m = fmaxf(m, __shfl_xor(m, 2)); m = fmaxf(m, __shfl_xor(m, 1));
  float s = 0.f;
  for (int j = l; j < c; j += 16) {
    float w = __expf(e[h * EPAD + j] - m);
    e[h * EPAD + j] = w;
    s += w;
  }
  s += __shfl_xor(s, 8); s += __shfl_xor(s, 4);
  s += __shfl_xor(s, 2); s += __shfl_xor(s, 1);
  float rs = 1.f / s;
  __syncthreads();
  // aggregate neighbors: thread (h, d=l)
  float acc = 0.f;
#pragma unroll 4
  for (int j = 0; j < c; ++j)
    acc += e[h * EPAD + j] * Wh1[(size_t)snb[j] * NCOL + t];
  acc *= rs;
  hs[t] = acc > 0.f ? acc : (__expf(acc) - 1.f);  // ELU
  __syncthreads();
  // fused layer-2 projection across all 128 threads
  int cc = t & 15, kg = t >> 4;
  float p = 0.f;
#pragma unroll
  for (int k = 0; k < 16; ++k)
    p += hs[kg * 16 + k] * Wout[(kg * 16 + k) * NCLASS + cc];
  part[kg][cc] = p;
  __syncthreads();
  if (t < NCLASS) {
    float a = 0.f;
#pragma unroll
    for (int kg2 = 0; kg2 < NHEADS; ++kg2) a += part[kg2][t];
    Wh2[n * NCLASS + t] = a;
    float vs = a * a2s[t], vd = a * a2d[t];
#pragma unroll
    for (int off = 8; off >= 1; off >>= 1) {
      vs += __shfl_xor(vs, off);
      vd += __shfl_xor(vd, off);
    }
    if (t == 0) { src2[n] = vs; dst2[n] = vd; }
  }
}

// ---------------------------------------------------------------------------
// Layer-2 masked softmax + aggregation + final ELU. 16 threads per node.
// ---------------------------------------------------------------------------
__global__ __launch_bounds__(256) void layer2_agg_kernel(
    const int* __restrict__ nbr, const int* __restrict__ cnt,
    const float* __restrict__ Wh2, const float* __restrict__ src2,
    const float* __restrict__ dst2, float* __restrict__ out) {
  int g = threadIdx.x >> 4, d = threadIdx.x & 15;
  int n = blockIdx.x * 16 + g;
  int c = cnt[n];
  const int* nb = nbr + (size_t)n * MAXN;
  float si = src2[n];
  float m = -1e30f;
#pragma unroll 4
  for (int j = 0; j < c; ++j) {
    float ee = si + dst2[nb[j]];
    ee = ee > 0.f ? ee : LALPHA * ee;
    m = fmaxf(m, ee);
  }
  float s = 0.f, acc = 0.f;
#pragma unroll 2
  for (int j = 0; j < c; ++j) {
    int jj = nb[j];
    float ee = si + dst2[jj];
    ee = ee > 0.f ? ee : LALPHA * ee;
    float w = __expf(ee - m);
    s += w;
    acc += w * Wh2[jj * NCLASS + d];
  }
  acc /= s;
  out[n * NCLASS + d] = acc > 0.f ? acc : (__expf(acc) - 1.f);
}

extern "C" void kernel_launch(void* const* d_in, const int* in_sizes, int n_in,
                              void* d_out, int out_size, void* d_ws, size_t ws_size,
                              hipStream_t stream) {
  const float* x     = (const float*)d_in[0];
  const float* adj   = (const float*)d_in[1];
  const float* W     = (const float*)d_in[2];
  const float* a_src = (const float*)d_in[3];
  const float* a_dst = (const float*)d_in[4];
  const float* W_out = (const float*)d_in[5];
  const float* a_os  = (const float*)d_in[6];
  const float* a_od  = (const float*)d_in[7];
  float* out = (float*)d_out;

  char* ws = (char*)d_ws;
  size_t off = 0;
  auto alloc = [&](size_t bytes) -> void* {
    void* p = ws + off;
    off += (bytes + 255) & ~(size_t)255;
    return p;
  };
  int*   nbr  = (int*)alloc((size_t)NN * MAXN * sizeof(int));
  int*   cnt  = (int*)alloc((size_t)NN * sizeof(int));
  float* Wh1  = (float*)alloc((size_t)NN * NCOL * sizeof(float));
  float* src1 = (float*)alloc((size_t)NN * NHEADS * sizeof(float));
  float* dst1 = (float*)alloc((size_t)NN * NHEADS * sizeof(float));
  float* Wh2  = (float*)alloc((size_t)NN * NCLASS * sizeof(float));
  float* src2 = (float*)alloc((size_t)NN * sizeof(float));
  float* dst2 = (float*)alloc((size_t)NN * sizeof(float));

  hipLaunchKernelGGL(prep_kernel, dim3(NN + NN / BNODES), dim3(256), 0, stream,
                     adj, x, W, a_src, a_dst, nbr, cnt, Wh1, src1, dst1);
  hipLaunchKernelGGL(layer1_agg_kernel, dim3(NN), dim3(128), 0, stream,
                     nbr, cnt, Wh1, src1, dst1, W_out, a_os, a_od, Wh2, src2, dst2);
  hipLaunchKernelGGL(layer2_agg_kernel, dim3(NN / 16), dim3(256), 0, stream,
                     nbr, cnt, Wh2, src2, dst2, out);
}

// Round 8
// 161.377 us; speedup vs baseline: 1.0617x; 1.0258x over previous
//
#include <hip/hip_runtime.h>

#define NN 4096
#define NFEAT 256
#define NHID 16
#define NHEADS 8
#define NCOL 128   // NHEADS*NHID
#define NCLASS 16
#define MAXN 256
#define LALPHA 0.2f
#define BNODES 16      // nodes per projection tile
#define NPROJ (NN / BNODES)  // 256 projection blocks, placed FIRST in grid
#define XPAD 20        // xT row stride in floats
#define EPAD 260       // e row stride

// ---------------------------------------------------------------------------
// Fused prep kernel.
//   blocks [0, NPROJ):           16-node tile of Wh1 = x@W + src1/dst1 logits
//   blocks [NPROJ, NPROJ+4*NN):  quarter-row adj compaction, one float4/lane,
//                                ballot + ONE global atomicAdd per wave.
// B blocks first so they overlap the A flood.
// ---------------------------------------------------------------------------
__global__ __launch_bounds__(256) void prep_kernel(
    const float* __restrict__ adj, const float* __restrict__ x,
    const float* __restrict__ W, const float* __restrict__ a_src,
    const float* __restrict__ a_dst,
    int* __restrict__ nbr, int* __restrict__ cnt,
    float* __restrict__ Wh1, float* __restrict__ src1, float* __restrict__ dst1) {
  __shared__ float xT[NFEAT * XPAD];  // used by B path only
  int t = threadIdx.x;

  if (blockIdx.x >= NPROJ) {
    // ---- A: compact a quarter of one adjacency row ----
    int bid = blockIdx.x - NPROJ;
    int row = bid >> 2, quarter = bid & 3;
    const float4* arow =
        reinterpret_cast<const float4*>(adj + (size_t)row * NN) + quarter * 256;
    float4 v = arow[t];
    int lane = t & 63;
    unsigned long long below = lane ? (~0ULL >> (64 - lane)) : 0ULL;
    unsigned long long m0 = __ballot(v.x > 0.f);
    unsigned long long m1 = __ballot(v.y > 0.f);
    unsigned long long m2 = __ballot(v.z > 0.f);
    unsigned long long m3 = __ballot(v.w > 0.f);
    int c0 = __popcll(m0), c1 = __popcll(m1), c2 = __popcll(m2), c3 = __popcll(m3);
    int tot = c0 + c1 + c2 + c3;
    int wbase = 0;
    if (lane == 0 && tot) wbase = atomicAdd(&cnt[row], tot);
    wbase = __shfl(wbase, 0);
    int* rn = nbr + (size_t)row * MAXN;
    int base = quarter * 1024 + t * 4;
    if (v.x > 0.f) { int p = wbase + __popcll(m0 & below);                if (p < MAXN) rn[p] = base;     }
    if (v.y > 0.f) { int p = wbase + c0 + __popcll(m1 & below);           if (p < MAXN) rn[p] = base + 1; }
    if (v.z > 0.f) { int p = wbase + c0 + c1 + __popcll(m2 & below);      if (p < MAXN) rn[p] = base + 2; }
    if (v.w > 0.f) { int p = wbase + c0 + c1 + c2 + __popcll(m3 & below); if (p < MAXN) rn[p] = base + 3; }
  } else {
    // ---- B: projection tile (16 nodes), 2 nodes x 4 cols per thread ----
    int bn = blockIdx.x * BNODES;
#pragma unroll
    for (int it = 0; it < BNODES; ++it) {
      xT[t * XPAD + it] = x[(size_t)(bn + it) * NFEAT + t];
    }
    __syncthreads();
    int cg = t & 31, ng = t >> 5;  // cols cg*4..+3, nodes ng*2..+1
    const float* Wp = W + (cg >> 2) * (NFEAT * NHID) + ((cg & 3) << 2);
    float acc[2][4] = {};
#pragma unroll 4
    for (int f = 0; f < NFEAT; ++f) {
      float4 wv = *reinterpret_cast<const float4*>(Wp + f * NHID);
      float2 xv = *reinterpret_cast<const float2*>(&xT[f * XPAD + ng * 2]);
      acc[0][0] += xv.x * wv.x; acc[0][1] += xv.x * wv.y;
      acc[0][2] += xv.x * wv.z; acc[0][3] += xv.x * wv.w;
      acc[1][0] += xv.y * wv.x; acc[1][1] += xv.y * wv.y;
      acc[1][2] += xv.y * wv.z; acc[1][3] += xv.y * wv.w;
    }
    int col0 = cg * 4;
    float4 as4 = *reinterpret_cast<const float4*>(a_src + col0);
    float4 ad4 = *reinterpret_cast<const float4*>(a_dst + col0);
#pragma unroll
    for (int i = 0; i < 2; ++i) {
      int n = bn + ng * 2 + i;
      *reinterpret_cast<float4*>(Wh1 + (size_t)n * NCOL + col0) =
          make_float4(acc[i][0], acc[i][1], acc[i][2], acc[i][3]);
      float vs = acc[i][0] * as4.x + acc[i][1] * as4.y + acc[i][2] * as4.z + acc[i][3] * as4.w;
      float vd = acc[i][0] * ad4.x + acc[i][1] * ad4.y + acc[i][2] * ad4.z + acc[i][3] * ad4.w;
      vs += __shfl_xor(vs, 1); vs += __shfl_xor(vs, 2);
      vd += __shfl_xor(vd, 1); vd += __shfl_xor(vd, 2);
      if ((cg & 3) == 0) {
        src1[n * NHEADS + (cg >> 2)] = vs;
        dst1[n * NHEADS + (cg >> 2)] = vd;
      }
    }
  }
}

// ---------------------------------------------------------------------------
// Layer-1 masked softmax + aggregation + ELU, fused with layer-2 projection.
// One block (128 threads = 8 heads x 16) per node.
// ---------------------------------------------------------------------------
__global__ __launch_bounds__(128) void layer1_agg_kernel(
    const int* __restrict__ nbr, const int* __restrict__ cnt,
    const float* __restrict__ Wh1, const float* __restrict__ src1,
    const float* __restrict__ dst1, const float* __restrict__ Wout,
    const float* __restrict__ a2s, const float* __restrict__ a2d,
    float* __restrict__ Wh2, float* __restrict__ src2, float* __restrict__ dst2) {
  int n = blockIdx.x, t = threadIdx.x;
  int h = t >> 4, l = t & 15;
  int c = cnt[n]; c = c < MAXN ? c : MAXN;
  __shared__ int snb[MAXN];
  __shared__ float e[NHEADS * EPAD];
  __shared__ float hs[NCOL];
  __shared__ float part[NHEADS][NCLASS];
  for (int j = t; j < c; j += 128) snb[j] = nbr[(size_t)n * MAXN + j];
  __syncthreads();
  // scores e[h][j] = leaky(src1[n,h] + dst1[nbr,h])
  for (int idx = t; idx < c * NHEADS; idx += 128) {
    int j = idx >> 3, hh = idx & 7;
    float ee = src1[n * NHEADS + hh] + dst1[snb[j] * NHEADS + hh];
    e[hh * EPAD + j] = ee > 0.f ? ee : LALPHA * ee;
  }
  __syncthreads();
  // per-head max + exp-sum, 16 lanes per head
  float m = -1e30f;
  for (int j = l; j < c; j += 16) m = fmaxf(m, e[h * EPAD + j]);
  m = fmaxf(m, __shfl_xor(m, 8)); m = fmaxf(m, __shfl_xor(m, 4));
  m = fmaxf(m, __shfl_xor(m, 2)); m = fmaxf(m, __shfl_xor(m, 1));
  float s = 0.f;
  for (int j = l; j < c; j += 16) {
    float w = __expf(e[h * EPAD + j] - m);
    e[h * EPAD + j] = w;
    s += w;
  }
  s += __shfl_xor(s, 8); s += __shfl_xor(s, 4);
  s += __shfl_xor(s, 2); s += __shfl_xor(s, 1);
  float rs = 1.f / s;
  __syncthreads();
  // aggregate neighbors: thread (h, d=l)
  float acc = 0.f;
#pragma unroll 8
  for (int j = 0; j < c; ++j)
    acc += e[h * EPAD + j] * Wh1[(size_t)snb[j] * NCOL + t];
  acc *= rs;
  hs[t] = acc > 0.f ? acc : (__expf(acc) - 1.f);  // ELU
  __syncthreads();
  // fused layer-2 projection across all 128 threads
  int cc = t & 15, kg = t >> 4;
  float p = 0.f;
#pragma unroll
  for (int k = 0; k < 16; ++k)
    p += hs[kg * 16 + k] * Wout[(kg * 16 + k) * NCLASS + cc];
  part[kg][cc] = p;
  __syncthreads();
  if (t < NCLASS) {
    float a = 0.f;
#pragma unroll
    for (int kg2 = 0; kg2 < NHEADS; ++kg2) a += part[kg2][t];
    Wh2[n * NCLASS + t] = a;
    float vs = a * a2s[t], vd = a * a2d[t];
#pragma unroll
    for (int off = 8; off >= 1; off >>= 1) {
      vs += __shfl_xor(vs, off);
      vd += __shfl_xor(vd, off);
    }
    if (t == 0) { src2[n] = vs; dst2[n] = vd; }
  }
}

// ---------------------------------------------------------------------------
// Layer-2 masked softmax + aggregation + final ELU.
// One WAVE per node (4 nodes per 256-thread block, grid 1024).
// Within a wave: d = lane&15 (class), g = lane>>4 (4-way neighbor split).
// ---------------------------------------------------------------------------
__global__ __launch_bounds__(256) void layer2_agg_kernel(
    const int* __restrict__ nbr, const int* __restrict__ cnt,
    const float* __restrict__ Wh2, const float* __restrict__ src2,
    const float* __restrict__ dst2, float* __restrict__ out) {
  int wave = threadIdx.x >> 6;
  int lane = threadIdx.x & 63;
  int d = lane & 15, g = lane >> 4;
  int n = blockIdx.x * 4 + wave;
  int c = cnt[n]; c = c < MAXN ? c : MAXN;
  const int* nb = nbr + (size_t)n * MAXN;
  float si = src2[n];
  // pass 1: max (4-way parallel over neighbors)
  float m = -1e30f;
  for (int j = g; j < c; j += 4) {
    float ee = si + dst2[nb[j]];
    ee = ee > 0.f ? ee : LALPHA * ee;
    m = fmaxf(m, ee);
  }
  m = fmaxf(m, __shfl_xor(m, 16));
  m = fmaxf(m, __shfl_xor(m, 32));
  // pass 2: exp-sum + weighted aggregation (loads L1-hot)
  float s = 0.f, acc = 0.f;
  for (int j = g; j < c; j += 4) {
    int jj = nb[j];
    float ee = si + dst2[jj];
    ee = ee > 0.f ? ee : LALPHA * ee;
    float w = __expf(ee - m);
    s += w;
    acc += w * Wh2[jj * NCLASS + d];
  }
  s += __shfl_xor(s, 16); s += __shfl_xor(s, 32);
  acc += __shfl_xor(acc, 16); acc += __shfl_xor(acc, 32);
  if (g == 0) {
    acc /= s;
    out[n * NCLASS + d] = acc > 0.f ? acc : (__expf(acc) - 1.f);
  }
}

extern "C" void kernel_launch(void* const* d_in, const int* in_sizes, int n_in,
                              void* d_out, int out_size, void* d_ws, size_t ws_size,
                              hipStream_t stream) {
  const float* x     = (const float*)d_in[0];
  const float* adj   = (const float*)d_in[1];
  const float* W     = (const float*)d_in[2];
  const float* a_src = (const float*)d_in[3];
  const float* a_dst = (const float*)d_in[4];
  const float* W_out = (const float*)d_in[5];
  const float* a_os  = (const float*)d_in[6];
  const float* a_od  = (const float*)d_in[7];
  float* out = (float*)d_out;

  char* ws = (char*)d_ws;
  size_t off = 0;
  auto alloc = [&](size_t bytes) -> void* {
    void* p = ws + off;
    off += (bytes + 255) & ~(size_t)255;
    return p;
  };
  int*   nbr  = (int*)alloc((size_t)NN * MAXN * sizeof(int));
  int*   cnt  = (int*)alloc((size_t)NN * sizeof(int));
  float* Wh1  = (float*)alloc((size_t)NN * NCOL * sizeof(float));
  float* src1 = (float*)alloc((size_t)NN * NHEADS * sizeof(float));
  float* dst1 = (float*)alloc((size_t)NN * NHEADS * sizeof(float));
  float* Wh2  = (float*)alloc((size_t)NN * NCLASS * sizeof(float));
  float* src2 = (float*)alloc((size_t)NN * sizeof(float));
  float* dst2 = (float*)alloc((size_t)NN * sizeof(float));

  // zero the per-row atomic counters (ws arrives poisoned 0xAA)
  hipMemsetAsync(cnt, 0, NN * sizeof(int), stream);
  hipLaunchKernelGGL(prep_kernel, dim3(NPROJ + 4 * NN), dim3(256), 0, stream,
                     adj, x, W, a_src, a_dst, nbr, cnt, Wh1, src1, dst1);
  hipLaunchKernelGGL(layer1_agg_kernel, dim3(NN), dim3(128), 0, stream,
                     nbr, cnt, Wh1, src1, dst1, W_out, a_os, a_od, Wh2, src2, dst2);
  hipLaunchKernelGGL(layer2_agg_kernel, dim3(NN / 4), dim3(256), 0, stream,
                     nbr, cnt, Wh2, src2, dst2, out);
}

// Round 10
// 152.991 us; speedup vs baseline: 1.1199x; 1.0548x over previous
//
#include <hip/hip_runtime.h>

#define NN 4096
#define NFEAT 256
#define NHID 16
#define NHEADS 8
#define NCOL 128   // NHEADS*NHID
#define NCLASS 16
#define MAXN 256
#define LALPHA 0.2f
#define BNODES 16      // nodes per projection tile
#define NPROJ (NN / BNODES)  // 256 projection blocks, placed FIRST in grid
#define XPAD 20        // xT row stride in floats
#define EPAD 260       // e row stride

// ---------------------------------------------------------------------------
// Fused prep kernel.
//   blocks [0, NPROJ):        16-node tile of Wh1 = x@W + src1/dst1 logits
//   blocks [NPROJ, NPROJ+NN): one FULL adj row per block; each thread loads
//                             4 independent float4s up front (MLP=4), then
//                             runs 4 ballot-compaction chunks on register data.
// ---------------------------------------------------------------------------
__global__ __launch_bounds__(256) void prep_kernel(
    const float* __restrict__ adj, const float* __restrict__ x,
    const float* __restrict__ W, const float* __restrict__ a_src,
    const float* __restrict__ a_dst,
    int* __restrict__ nbr, int* __restrict__ cnt,
    float* __restrict__ Wh1, float* __restrict__ src1, float* __restrict__ dst1) {
  __shared__ float xT[NFEAT * XPAD];  // used by B path only
  int t = threadIdx.x;

  if (blockIdx.x >= NPROJ) {
    // ---- A: compact one full adjacency row, 4 chunks in registers ----
    int row = blockIdx.x - NPROJ;
    const float4* arow = reinterpret_cast<const float4*>(adj + (size_t)row * NN);
    // 4 independent loads issued before any dependent work (vmcnt batching)
    float4 v0 = arow[t];
    float4 v1 = arow[t + 256];
    float4 v2 = arow[t + 512];
    float4 v3 = arow[t + 768];
    int lane = t & 63;
    unsigned long long below = lane ? (~0ULL >> (64 - lane)) : 0ULL;
    int* rn = nbr + (size_t)row * MAXN;
    float4 vv[4] = {v0, v1, v2, v3};
#pragma unroll
    for (int q = 0; q < 4; ++q) {
      float4 v = vv[q];
      int base = (t + q * 256) * 4;
      unsigned long long m0 = __ballot(v.x > 0.f);
      unsigned long long m1 = __ballot(v.y > 0.f);
      unsigned long long m2 = __ballot(v.z > 0.f);
      unsigned long long m3 = __ballot(v.w > 0.f);
      int c0 = __popcll(m0), c1 = __popcll(m1), c2 = __popcll(m2), c3 = __popcll(m3);
      int tot = c0 + c1 + c2 + c3;
      int wbase = 0;
      if (lane == 0 && tot) wbase = atomicAdd(&cnt[row], tot);
      wbase = __shfl(wbase, 0);
      if (v.x > 0.f) { int p = wbase + __popcll(m0 & below);                if (p < MAXN) rn[p] = base;     }
      if (v.y > 0.f) { int p = wbase + c0 + __popcll(m1 & below);           if (p < MAXN) rn[p] = base + 1; }
      if (v.z > 0.f) { int p = wbase + c0 + c1 + __popcll(m2 & below);      if (p < MAXN) rn[p] = base + 2; }
      if (v.w > 0.f) { int p = wbase + c0 + c1 + c2 + __popcll(m3 & below); if (p < MAXN) rn[p] = base + 3; }
    }
  } else {
    // ---- B: projection tile (16 nodes), 2 nodes x 4 cols per thread ----
    int bn = blockIdx.x * BNODES;
#pragma unroll
    for (int it = 0; it < BNODES; ++it) {
      xT[t * XPAD + it] = x[(size_t)(bn + it) * NFEAT + t];
    }
    __syncthreads();
    int cg = t & 31, ng = t >> 5;  // cols cg*4..+3, nodes ng*2..+1
    const float* Wp = W + (cg >> 2) * (NFEAT * NHID) + ((cg & 3) << 2);
    float acc[2][4] = {};
#pragma unroll 4
    for (int f = 0; f < NFEAT; ++f) {
      float4 wv = *reinterpret_cast<const float4*>(Wp + f * NHID);
      float2 xv = *reinterpret_cast<const float2*>(&xT[f * XPAD + ng * 2]);
      acc[0][0] += xv.x * wv.x; acc[0][1] += xv.x * wv.y;
      acc[0][2] += xv.x * wv.z; acc[0][3] += xv.x * wv.w;
      acc[1][0] += xv.y * wv.x; acc[1][1] += xv.y * wv.y;
      acc[1][2] += xv.y * wv.z; acc[1][3] += xv.y * wv.w;
    }
    int col0 = cg * 4;
    float4 as4 = *reinterpret_cast<const float4*>(a_src + col0);
    float4 ad4 = *reinterpret_cast<const float4*>(a_dst + col0);
#pragma unroll
    for (int i = 0; i < 2; ++i) {
      int n = bn + ng * 2 + i;
      *reinterpret_cast<float4*>(Wh1 + (size_t)n * NCOL + col0) =
          make_float4(acc[i][0], acc[i][1], acc[i][2], acc[i][3]);
      float vs = acc[i][0] * as4.x + acc[i][1] * as4.y + acc[i][2] * as4.z + acc[i][3] * as4.w;
      float vd = acc[i][0] * ad4.x + acc[i][1] * ad4.y + acc[i][2] * ad4.z + acc[i][3] * ad4.w;
      vs += __shfl_xor(vs, 1); vs += __shfl_xor(vs, 2);
      vd += __shfl_xor(vd, 1); vd += __shfl_xor(vd, 2);
      if ((cg & 3) == 0) {
        src1[n * NHEADS + (cg >> 2)] = vs;
        dst1[n * NHEADS + (cg >> 2)] = vd;
      }
    }
  }
}

// ---------------------------------------------------------------------------
// Layer-1 masked softmax + aggregation + ELU, fused with layer-2 projection.
// One block (128 threads = 8 heads x 16) per node.
// ---------------------------------------------------------------------------
__global__ __launch_bounds__(128) void layer1_agg_kernel(
    const int* __restrict__ nbr, const int* __restrict__ cnt,
    const float* __restrict__ Wh1, const float* __restrict__ src1,
    const float* __restrict__ dst1, const float* __restrict__ Wout,
    const float* __restrict__ a2s, const float* __restrict__ a2d,
    float* __restrict__ Wh2, float* __restrict__ src2, float* __restrict__ dst2) {
  int n = blockIdx.x, t = threadIdx.x;
  int h = t >> 4, l = t & 15;
  int c = cnt[n]; c = c < MAXN ? c : MAXN;
  __shared__ int snb[MAXN];
  __shared__ float e[NHEADS * EPAD];
  __shared__ float hs[NCOL];
  __shared__ float part[NHEADS][NCLASS];
  for (int j = t; j < c; j += 128) snb[j] = nbr[(size_t)n * MAXN + j];
  __syncthreads();
  // scores e[h][j] = leaky(src1[n,h] + dst1[nbr,h])
  for (int idx = t; idx < c * NHEADS; idx += 128) {
    int j = idx >> 3, hh = idx & 7;
    float ee = src1[n * NHEADS + hh] + dst1[snb[j] * NHEADS + hh];
    e[hh * EPAD + j] = ee > 0.f ? ee : LALPHA * ee;
  }
  __syncthreads();
  // per-head max + exp-sum, 16 lanes per head
  float m = -1e30f;
  for (int j = l; j < c; j += 16) m = fmaxf(m, e[h * EPAD + j]);
  m = fmaxf(m, __shfl_xor(m, 8)); m = fmaxf(m, __shfl_xor(m, 4));
  m = fmaxf(m, __shfl_xor(m, 2)); m = fmaxf(m, __shfl_xor(m, 1));
  float s = 0.f;
  for (int j = l; j < c; j += 16) {
    float w = __expf(e[h * EPAD + j] - m);
    e[h * EPAD + j] = w;
    s += w;
  }
  s += __shfl_xor(s, 8); s += __shfl_xor(s, 4);
  s += __shfl_xor(s, 2); s += __shfl_xor(s, 1);
  float rs = 1.f / s;
  __syncthreads();
  // aggregate neighbors: thread (h, d=l)
  float acc = 0.f;
#pragma unroll 8
  for (int j = 0; j < c; ++j)
    acc += e[h * EPAD + j] * Wh1[(size_t)snb[j] * NCOL + t];
  acc *= rs;
  hs[t] = acc > 0.f ? acc : (__expf(acc) - 1.f);  // ELU
  __syncthreads();
  // fused layer-2 projection across all 128 threads
  int cc = t & 15, kg = t >> 4;
  float p = 0.f;
#pragma unroll
  for (int k = 0; k < 16; ++k)
    p += hs[kg * 16 + k] * Wout[(kg * 16 + k) * NCLASS + cc];
  part[kg][cc] = p;
  __syncthreads();
  if (t < NCLASS) {
    float a = 0.f;
#pragma unroll
    for (int kg2 = 0; kg2 < NHEADS; ++kg2) a += part[kg2][t];
    Wh2[n * NCLASS + t] = a;
    float vs = a * a2s[t], vd = a * a2d[t];
#pragma unroll
    for (int off = 8; off >= 1; off >>= 1) {
      vs += __shfl_xor(vs, off);
      vd += __shfl_xor(vd, off);
    }
    if (t == 0) { src2[n] = vs; dst2[n] = vd; }
  }
}

// ---------------------------------------------------------------------------
// Layer-2 masked softmax + aggregation + final ELU.
// One WAVE per node (4 nodes per 256-thread block, grid 1024).
// ---------------------------------------------------------------------------
__global__ __launch_bounds__(256) void layer2_agg_kernel(
    const int* __restrict__ nbr, const int* __restrict__ cnt,
    const float* __restrict__ Wh2, const float* __restrict__ src2,
    const float* __restrict__ dst2, float* __restrict__ out) {
  int wave = threadIdx.x >> 6;
  int lane = threadIdx.x & 63;
  int d = lane & 15, g = lane >> 4;
  int n = blockIdx.x * 4 + wave;
  int c = cnt[n]; c = c < MAXN ? c : MAXN;
  const int* nb = nbr + (size_t)n * MAXN;
  float si = src2[n];
  // pass 1: max (4-way parallel over neighbors)
  float m = -1e30f;
  for (int j = g; j < c; j += 4) {
    float ee = si + dst2[nb[j]];
    ee = ee > 0.f ? ee : LALPHA * ee;
    m = fmaxf(m, ee);
  }
  m = fmaxf(m, __shfl_xor(m, 16));
  m = fmaxf(m, __shfl_xor(m, 32));
  // pass 2: exp-sum + weighted aggregation (loads L1-hot)
  float s = 0.f, acc = 0.f;
  for (int j = g; j < c; j += 4) {
    int jj = nb[j];
    float ee = si + dst2[jj];
    ee = ee > 0.f ? ee : LALPHA * ee;
    float w = __expf(ee - m);
    s += w;
    acc += w * Wh2[jj * NCLASS + d];
  }
  s += __shfl_xor(s, 16); s += __shfl_xor(s, 32);
  acc += __shfl_xor(acc, 16); acc += __shfl_xor(acc, 32);
  if (g == 0) {
    acc /= s;
    out[n * NCLASS + d] = acc > 0.f ? acc : (__expf(acc) - 1.f);
  }
}

extern "C" void kernel_launch(void* const* d_in, const int* in_sizes, int n_in,
                              void* d_out, int out_size, void* d_ws, size_t ws_size,
                              hipStream_t stream) {
  const float* x     = (const float*)d_in[0];
  const float* adj   = (const float*)d_in[1];
  const float* W     = (const float*)d_in[2];
  const float* a_src = (const float*)d_in[3];
  const float* a_dst = (const float*)d_in[4];
  const float* W_out = (const float*)d_in[5];
  const float* a_os  = (const float*)d_in[6];
  const float* a_od  = (const float*)d_in[7];
  float* out = (float*)d_out;

  char* ws = (char*)d_ws;
  size_t off = 0;
  auto alloc = [&](size_t bytes) -> void* {
    void* p = ws + off;
    off += (bytes + 255) & ~(size_t)255;
    return p;
  };
  int*   nbr  = (int*)alloc((size_t)NN * MAXN * sizeof(int));
  int*   cnt  = (int*)alloc((size_t)NN * sizeof(int));
  float* Wh1  = (float*)alloc((size_t)NN * NCOL * sizeof(float));
  float* src1 = (float*)alloc((size_t)NN * NHEADS * sizeof(float));
  float* dst1 = (float*)alloc((size_t)NN * NHEADS * sizeof(float));
  float* Wh2  = (float*)alloc((size_t)NN * NCLASS * sizeof(float));
  float* src2 = (float*)alloc((size_t)NN * sizeof(float));
  float* dst2 = (float*)alloc((size_t)NN * sizeof(float));

  // zero the per-row atomic counters (ws arrives poisoned 0xAA)
  hipMemsetAsync(cnt, 0, NN * sizeof(int), stream);
  hipLaunchKernelGGL(prep_kernel, dim3(NPROJ + NN), dim3(256), 0, stream,
                     adj, x, W, a_src, a_dst, nbr, cnt, Wh1, src1, dst1);
  hipLaunchKernelGGL(layer1_agg_kernel, dim3(NN), dim3(128), 0, stream,
                     nbr, cnt, Wh1, src1, dst1, W_out, a_os, a_od, Wh2, src2, dst2);
  hipLaunchKernelGGL(layer2_agg_kernel, dim3(NN / 4), dim3(256), 0, stream,
                     nbr, cnt, Wh2, src2, dst2, out);
}

// Round 11
// 143.820 us; speedup vs baseline: 1.1913x; 1.0638x over previous
//
#include <hip/hip_runtime.h>

#define NN 4096
#define NFEAT 256
#define NHID 16
#define NHEADS 8
#define NCOL 128   // NHEADS*NHID
#define NCLASS 16
#define MAXN 256
#define LALPHA 0.2f
#define BNODES 16            // nodes per projection tile
#define NPROJ (NN / BNODES)  // 256 projection blocks, placed FIRST in grid
#define XPAD 18              // xT row stride (18*4B=72B: 8B-aligned float2 reads)
#define EPAD 260             // e row stride

// ---------------------------------------------------------------------------
// Fused prep kernel.
//   blocks [0, NPROJ):        16-node tile of Wh1 = x@W + src1/dst1 logits
//   blocks [NPROJ, NPROJ+NN): one FULL adj row per block. ATOMIC-FREE:
//     ballot counts -> LDS -> block scan (1 barrier) -> deterministic scatter.
//     cnt[row] written directly (no memset, no global atomics).
// ---------------------------------------------------------------------------
__global__ __launch_bounds__(256) void prep_kernel(
    const float* __restrict__ adj, const float* __restrict__ x,
    const float* __restrict__ W, const float* __restrict__ a_src,
    const float* __restrict__ a_dst,
    int* __restrict__ nbr, int* __restrict__ cnt,
    float* __restrict__ Wh1, float* __restrict__ src1, float* __restrict__ dst1) {
  __shared__ float xT[NFEAT * XPAD];  // 18.4 KB; A path reuses first 64 B
  int t = threadIdx.x;

  if (blockIdx.x >= NPROJ) {
    // ---- A: compact one full adjacency row, no atomics ----
    int row = blockIdx.x - NPROJ;
    int* scnt = reinterpret_cast<int*>(xT);  // 16 ints: count per (wave,q)
    const float4* arow = reinterpret_cast<const float4*>(adj + (size_t)row * NN);
    float4 v0 = arow[t];
    float4 v1 = arow[t + 256];
    float4 v2 = arow[t + 512];
    float4 v3 = arow[t + 768];
    int wave = t >> 6, lane = t & 63;
    unsigned long long below = lane ? (~0ULL >> (64 - lane)) : 0ULL;
    float4 vv[4] = {v0, v1, v2, v3};       // unrolled const-index only
    unsigned long long mm[4][4];
    int cc[4][4], tot[4];
#pragma unroll
    for (int q = 0; q < 4; ++q) {
      mm[q][0] = __ballot(vv[q].x > 0.f);
      mm[q][1] = __ballot(vv[q].y > 0.f);
      mm[q][2] = __ballot(vv[q].z > 0.f);
      mm[q][3] = __ballot(vv[q].w > 0.f);
      cc[q][0] = __popcll(mm[q][0]); cc[q][1] = __popcll(mm[q][1]);
      cc[q][2] = __popcll(mm[q][2]); cc[q][3] = __popcll(mm[q][3]);
      tot[q] = cc[q][0] + cc[q][1] + cc[q][2] + cc[q][3];
      if (lane == 0) scnt[wave * 4 + q] = tot[q];
    }
    __syncthreads();
    // per-wave base: sum of all chunks of earlier waves (broadcast LDS reads,
    // wave-uniform selects; within-wave q offsets come from local tot[]).
    int s0 = scnt[0] + scnt[1] + scnt[2] + scnt[3];
    int s1 = scnt[4] + scnt[5] + scnt[6] + scnt[7];
    int s2 = scnt[8] + scnt[9] + scnt[10] + scnt[11];
    int run = (wave > 0 ? s0 : 0) + (wave > 1 ? s1 : 0) + (wave > 2 ? s2 : 0);
    int* rn = nbr + (size_t)row * MAXN;
#pragma unroll
    for (int q = 0; q < 4; ++q) {
      int wb = run;
      run += tot[q];
      float4 v = vv[q];
      int gbase = (t + q * 256) * 4;
      if (v.x > 0.f) { int p = wb + __popcll(mm[q][0] & below);                         if (p < MAXN) rn[p] = gbase;     }
      if (v.y > 0.f) { int p = wb + cc[q][0] + __popcll(mm[q][1] & below);              if (p < MAXN) rn[p] = gbase + 1; }
      if (v.z > 0.f) { int p = wb + cc[q][0] + cc[q][1] + __popcll(mm[q][2] & below);   if (p < MAXN) rn[p] = gbase + 2; }
      if (v.w > 0.f) { int p = wb + cc[q][0] + cc[q][1] + cc[q][2] + __popcll(mm[q][3] & below); if (p < MAXN) rn[p] = gbase + 3; }
    }
    if (t == 255) cnt[row] = run < MAXN ? run : MAXN;  // wave3's running sum = grand total
  } else {
    // ---- B: projection tile (16 nodes), 2 nodes x 4 cols per thread ----
    int bn = blockIdx.x * BNODES;
#pragma unroll
    for (int it = 0; it < BNODES; ++it) {
      xT[t * XPAD + it] = x[(size_t)(bn + it) * NFEAT + t];
    }
    __syncthreads();
    int cg = t & 31, ng = t >> 5;  // cols cg*4..+3, nodes ng*2..+1
    const float* Wp = W + (cg >> 2) * (NFEAT * NHID) + ((cg & 3) << 2);
    float acc[2][4] = {};
#pragma unroll 4
    for (int f = 0; f < NFEAT; ++f) {
      float4 wv = *reinterpret_cast<const float4*>(Wp + f * NHID);
      float2 xv = *reinterpret_cast<const float2*>(&xT[f * XPAD + ng * 2]);
      acc[0][0] += xv.x * wv.x; acc[0][1] += xv.x * wv.y;
      acc[0][2] += xv.x * wv.z; acc[0][3] += xv.x * wv.w;
      acc[1][0] += xv.y * wv.x; acc[1][1] += xv.y * wv.y;
      acc[1][2] += xv.y * wv.z; acc[1][3] += xv.y * wv.w;
    }
    int col0 = cg * 4;
    float4 as4 = *reinterpret_cast<const float4*>(a_src + col0);
    float4 ad4 = *reinterpret_cast<const float4*>(a_dst + col0);
#pragma unroll
    for (int i = 0; i < 2; ++i) {
      int n = bn + ng * 2 + i;
      *reinterpret_cast<float4*>(Wh1 + (size_t)n * NCOL + col0) =
          make_float4(acc[i][0], acc[i][1], acc[i][2], acc[i][3]);
      float vs = acc[i][0] * as4.x + acc[i][1] * as4.y + acc[i][2] * as4.z + acc[i][3] * as4.w;
      float vd = acc[i][0] * ad4.x + acc[i][1] * ad4.y + acc[i][2] * ad4.z + acc[i][3] * ad4.w;
      vs += __shfl_xor(vs, 1); vs += __shfl_xor(vs, 2);
      vd += __shfl_xor(vd, 1); vd += __shfl_xor(vd, 2);
      if ((cg & 3) == 0) {
        src1[n * NHEADS + (cg >> 2)] = vs;
        dst1[n * NHEADS + (cg >> 2)] = vd;
      }
    }
  }
}

// ---------------------------------------------------------------------------
// Layer-1 masked softmax + aggregation + ELU, fused with layer-2 projection.
// One block (128 threads = 8 heads x 16) per node.  (unchanged this round)
// ---------------------------------------------------------------------------
__global__ __launch_bounds__(128) void layer1_agg_kernel(
    const int* __restrict__ nbr, const int* __restrict__ cnt,
    const float* __restrict__ Wh1, const float* __restrict__ src1,
    const float* __restrict__ dst1, const float* __restrict__ Wout,
    const float* __restrict__ a2s, const float* __restrict__ a2d,
    float* __restrict__ Wh2, float* __restrict__ src2, float* __restrict__ dst2) {
  int n = blockIdx.x, t = threadIdx.x;
  int h = t >> 4, l = t & 15;
  int c = cnt[n]; c = c < MAXN ? c : MAXN;
  __shared__ int snb[MAXN];
  __shared__ float e[NHEADS * EPAD];
  __shared__ float hs[NCOL];
  __shared__ float part[NHEADS][NCLASS];
  for (int j = t; j < c; j += 128) snb[j] = nbr[(size_t)n * MAXN + j];
  __syncthreads();
  for (int idx = t; idx < c * NHEADS; idx += 128) {
    int j = idx >> 3, hh = idx & 7;
    float ee = src1[n * NHEADS + hh] + dst1[snb[j] * NHEADS + hh];
    e[hh * EPAD + j] = ee > 0.f ? ee : LALPHA * ee;
  }
  __syncthreads();
  float m = -1e30f;
  for (int j = l; j < c; j += 16) m = fmaxf(m, e[h * EPAD + j]);
  m = fmaxf(m, __shfl_xor(m, 8)); m = fmaxf(m, __shfl_xor(m, 4));
  m = fmaxf(m, __shfl_xor(m, 2)); m = fmaxf(m, __shfl_xor(m, 1));
  float s = 0.f;
  for (int j = l; j < c; j += 16) {
    float w = __expf(e[h * EPAD + j] - m);
    e[h * EPAD + j] = w;
    s += w;
  }
  s += __shfl_xor(s, 8); s += __shfl_xor(s, 4);
  s += __shfl_xor(s, 2); s += __shfl_xor(s, 1);
  float rs = 1.f / s;
  __syncthreads();
  float acc = 0.f;
#pragma unroll 8
  for (int j = 0; j < c; ++j)
    acc += e[h * EPAD + j] * Wh1[(size_t)snb[j] * NCOL + t];
  acc *= rs;
  hs[t] = acc > 0.f ? acc : (__expf(acc) - 1.f);
  __syncthreads();
  int cc = t & 15, kg = t >> 4;
  float p = 0.f;
#pragma unroll
  for (int k = 0; k < 16; ++k)
    p += hs[kg * 16 + k] * Wout[(kg * 16 + k) * NCLASS + cc];
  part[kg][cc] = p;
  __syncthreads();
  if (t < NCLASS) {
    float a = 0.f;
#pragma unroll
    for (int kg2 = 0; kg2 < NHEADS; ++kg2) a += part[kg2][t];
    Wh2[n * NCLASS + t] = a;
    float vs = a * a2s[t], vd = a * a2d[t];
#pragma unroll
    for (int off = 8; off >= 1; off >>= 1) {
      vs += __shfl_xor(vs, off);
      vd += __shfl_xor(vd, off);
    }
    if (t == 0) { src2[n] = vs; dst2[n] = vd; }
  }
}

// ---------------------------------------------------------------------------
// Layer-2 masked softmax + aggregation + final ELU.  (unchanged this round)
// One WAVE per node (4 nodes per 256-thread block, grid 1024).
// ---------------------------------------------------------------------------
__global__ __launch_bounds__(256) void layer2_agg_kernel(
    const int* __restrict__ nbr, const int* __restrict__ cnt,
    const float* __restrict__ Wh2, const float* __restrict__ src2,
    const float* __restrict__ dst2, float* __restrict__ out) {
  int wave = threadIdx.x >> 6;
  int lane = threadIdx.x & 63;
  int d = lane & 15, g = lane >> 4;
  int n = blockIdx.x * 4 + wave;
  int c = cnt[n]; c = c < MAXN ? c : MAXN;
  const int* nb = nbr + (size_t)n * MAXN;
  float si = src2[n];
  float m = -1e30f;
  for (int j = g; j < c; j += 4) {
    float ee = si + dst2[nb[j]];
    ee = ee > 0.f ? ee : LALPHA * ee;
    m = fmaxf(m, ee);
  }
  m = fmaxf(m, __shfl_xor(m, 16));
  m = fmaxf(m, __shfl_xor(m, 32));
  float s = 0.f, acc = 0.f;
  for (int j = g; j < c; j += 4) {
    int jj = nb[j];
    float ee = si + dst2[jj];
    ee = ee > 0.f ? ee : LALPHA * ee;
    float w = __expf(ee - m);
    s += w;
    acc += w * Wh2[jj * NCLASS + d];
  }
  s += __shfl_xor(s, 16); s += __shfl_xor(s, 32);
  acc += __shfl_xor(acc, 16); acc += __shfl_xor(acc, 32);
  if (g == 0) {
    acc /= s;
    out[n * NCLASS + d] = acc > 0.f ? acc : (__expf(acc) - 1.f);
  }
}

extern "C" void kernel_launch(void* const* d_in, const int* in_sizes, int n_in,
                              void* d_out, int out_size, void* d_ws, size_t ws_size,
                              hipStream_t stream) {
  const float* x     = (const float*)d_in[0];
  const float* adj   = (const float*)d_in[1];
  const float* W     = (const float*)d_in[2];
  const float* a_src = (const float*)d_in[3];
  const float* a_dst = (const float*)d_in[4];
  const float* W_out = (const float*)d_in[5];
  const float* a_os  = (const float*)d_in[6];
  const float* a_od  = (const float*)d_in[7];
  float* out = (float*)d_out;

  char* ws = (char*)d_ws;
  size_t off = 0;
  auto alloc = [&](size_t bytes) -> void* {
    void* p = ws + off;
    off += (bytes + 255) & ~(size_t)255;
    return p;
  };
  int*   nbr  = (int*)alloc((size_t)NN * MAXN * sizeof(int));
  int*   cnt  = (int*)alloc((size_t)NN * sizeof(int));
  float* Wh1  = (float*)alloc((size_t)NN * NCOL * sizeof(float));
  float* src1 = (float*)alloc((size_t)NN * NHEADS * sizeof(float));
  float* dst1 = (float*)alloc((size_t)NN * NHEADS * sizeof(float));
  float* Wh2  = (float*)alloc((size_t)NN * NCLASS * sizeof(float));
  float* src2 = (float*)alloc((size_t)NN * sizeof(float));
  float* dst2 = (float*)alloc((size_t)NN * sizeof(float));

  // no memset needed: prep writes cnt[row] directly (atomic-free scan)
  hipLaunchKernelGGL(prep_kernel, dim3(NPROJ + NN), dim3(256), 0, stream,
                     adj, x, W, a_src, a_dst, nbr, cnt, Wh1, src1, dst1);
  hipLaunchKernelGGL(layer1_agg_kernel, dim3(NN), dim3(128), 0, stream,
                     nbr, cnt, Wh1, src1, dst1, W_out, a_os, a_od, Wh2, src2, dst2);
  hipLaunchKernelGGL(layer2_agg_kernel, dim3(NN / 4), dim3(256), 0, stream,
                     nbr, cnt, Wh2, src2, dst2, out);
}